// Round 10
// baseline (215.810 us; speedup 1.0000x reference)
//
#include <hip/hip_runtime.h>

// Mamba-2 SSD chunked scan — fused persistent kernel, round 10.
// Round-10 change vs r9: block = (p-QUARTER, h, b) -> 512 blocks x 256 threads
// (4 waves), LDS 69->54.8 KB => 2 blocks/CU. Two independent barrier domains
// per CU hide each other's barrier/latency stalls (r9 was 1 block/CU, 3
// barriers/chunk fully serialized). Per-CU MFMA work unchanged. B/C logically
// read 4x per (b,h) but chunk working set is KB-scale -> L2/L3 absorb.
// Per chunk c:  P1: G = C B^T (4 j-tiles/wave); ao = C St^T; stch = Bt x Xt
//               P2: M' = mask(G) e^{cs_i-cs63}; St = e^{cs63} St + stch;
//                   stage c+1; issue loads c+2
//               P3: ad = M' Xs; sY = ad + e^{cs} o ao     P4: Y store
// Canaries: WRITE_SIZE must be 131072 KB (no spill, no write-amp).

typedef __bf16 bf16x4 __attribute__((ext_vector_type(4)));
typedef __bf16 bf16x8 __attribute__((ext_vector_type(8)));
typedef float  f32x4  __attribute__((ext_vector_type(4)));

constexpr int LDT = 72;   // bf16 row stride (144 B)

__device__ __forceinline__ f32x4 mfma16(bf16x8 a, bf16x8 b, f32x4 c) {
    return __builtin_amdgcn_mfma_f32_16x16x32_bf16(a, b, c, 0, 0, 0);
}

struct SMemF {
    __bf16 Cm[64][LDT];      // C row-major [l][n]
    __bf16 Bm[64][LDT];      // B row-major [l][n]
    __bf16 Bt[64][LDT];      // B^T [n][l]
    __bf16 Mm[64][LDT];      // M' [i][j]
    __bf16 Xt[2][16][LDT];   // Xs^T [p][l], double-buffered (p-quarter)
    __bf16 St16[16][LDT];    // state bf16 (operand copy)
    float  St32[16][68];     // state f32 (master)
    float  sY[64][20];       // Y staging (p-quarter)
    float  ds[2][64];        // e^{cs63-cs_l}
    float  dout[2][64];      // e^{cs_i}
    float  douti[2][64];     // e^{cs_i-cs63}
    float  dlast[2];         // e^{cs63}
};

__global__ void ssd_fused(const float* __restrict__ Xg, const float* __restrict__ Ig,
                          const float* __restrict__ Ag, const float* __restrict__ Bg,
                          const float* __restrict__ Cg, float* __restrict__ Yg)
{
    const int ph = blockIdx.x, hh = blockIdx.y, bb = blockIdx.z;
    const int p0 = ph * 16;
    const int tid = threadIdx.x;            // 0..255
    const int wid = tid >> 6, lane = tid & 63;
    const int fr = lane & 15, fg = lane >> 4;
    const int iw2 = wid * 16;               // i-strip / n-strip (4 waves x 16)

    __shared__ __align__(16) SMemF sm;
    const size_t tbase = (size_t)bb * 4096;

    // staging maps
    const int lt0 = (tid >> 4) * 4;         // 4-row block (B,C)
    const int cq0 = (tid & 15) * 4;         // column quad
    const int xl  = tid >> 2;               // X/Y row 0..63
    const int xp4 = (tid & 3) * 4;          // X/Y p quad 0..12
    const int sp  = tid >> 4;               // St row 0..15
    const int sn4 = (tid & 15) * 4;

    float rbB[4][4], rbC[4][4], rx[4];
    float aA = 0.0f;

    // ---------------- prologue ----------------
    {   // initial state (p-quarter)
        const size_t iofs = (((size_t)bb*16 + hh)*64 + (p0 + sp))*(size_t)64 + sn4;
        const float4 v = *reinterpret_cast<const float4*>(&Ig[iofs]);
        sm.St32[sp][sn4+0] = v.x; sm.St32[sp][sn4+1] = v.y;
        sm.St32[sp][sn4+2] = v.z; sm.St32[sp][sn4+3] = v.w;
        *reinterpret_cast<bf16x4*>(&sm.St16[sp][sn4]) =
            (bf16x4){(__bf16)v.x, (__bf16)v.y, (__bf16)v.z, (__bf16)v.w};
    }
    // chunk-0 loads
    #pragma unroll
    for (int j = 0; j < 4; ++j) {
        const size_t go = ((tbase + lt0 + j)*16 + hh)*(size_t)64 + cq0;
        *reinterpret_cast<float4*>(rbB[j]) = *reinterpret_cast<const float4*>(&Bg[go]);
        *reinterpret_cast<float4*>(rbC[j]) = *reinterpret_cast<const float4*>(&Cg[go]);
    }
    *reinterpret_cast<float4*>(rx) =
        *reinterpret_cast<const float4*>(&Xg[((tbase + xl)*16 + hh)*(size_t)64 + p0 + xp4]);
    if (wid == 0) aA = Ag[(tbase + lane)*16 + hh];

    // scan chunk 0 -> tables[0]
    if (wid == 0) {
        float v = aA;
        #pragma unroll
        for (int o = 1; o < 64; o <<= 1) { float t = __shfl_up(v, o, 64); if (lane >= o) v += t; }
        const float last = __shfl(v, 63, 64);
        sm.ds[0][lane]    = expf(last - v);
        sm.dout[0][lane]  = expf(v);
        sm.douti[0][lane] = expf(v - last);
        if (lane == 63) sm.dlast[0] = expf(v);
    }
    // stage chunk-0 B/Bt/C (no table dependency)
    #pragma unroll
    for (int j = 0; j < 4; ++j) {
        *reinterpret_cast<bf16x4*>(&sm.Bm[lt0 + j][cq0]) =
            (bf16x4){(__bf16)rbB[j][0], (__bf16)rbB[j][1], (__bf16)rbB[j][2], (__bf16)rbB[j][3]};
        *reinterpret_cast<bf16x4*>(&sm.Cm[lt0 + j][cq0]) =
            (bf16x4){(__bf16)rbC[j][0], (__bf16)rbC[j][1], (__bf16)rbC[j][2], (__bf16)rbC[j][3]};
    }
    #pragma unroll
    for (int q = 0; q < 4; ++q)
        *reinterpret_cast<bf16x4*>(&sm.Bt[cq0 + q][lt0]) =
            (bf16x4){(__bf16)rbB[0][q], (__bf16)rbB[1][q], (__bf16)rbB[2][q], (__bf16)rbB[3][q]};
    __syncthreads();   // tables[0] + St + chunk0 C/B/Bt ready

    {   // stage Xs^T[0] (needs ds[0])
        const float dsl = sm.ds[0][xl];
        #pragma unroll
        for (int q = 0; q < 4; ++q) sm.Xt[0][xp4 + q][xl] = (__bf16)(rx[q] * dsl);
    }
    // chunk-1 loads
    #pragma unroll
    for (int j = 0; j < 4; ++j) {
        const size_t go = ((tbase + 64 + lt0 + j)*16 + hh)*(size_t)64 + cq0;
        *reinterpret_cast<float4*>(rbB[j]) = *reinterpret_cast<const float4*>(&Bg[go]);
        *reinterpret_cast<float4*>(rbC[j]) = *reinterpret_cast<const float4*>(&Cg[go]);
    }
    *reinterpret_cast<float4*>(rx) =
        *reinterpret_cast<const float4*>(&Xg[((tbase + 64 + xl)*16 + hh)*(size_t)64 + p0 + xp4]);
    if (wid == 0) aA = Ag[(tbase + 64 + lane)*16 + hh];
    __syncthreads();   // Xt[0] visible

    // ---------------- chunk loop ----------------
    for (int c = 0; c < 64; ++c) {
        const int ci = c & 1, nb = (c + 1) & 1;

        // ---- P1: MFMAs for chunk c (+ wave0 scans c+1) ----
        f32x4 g[4] = {}, aoacc = {}, stacc = {};
        #pragma unroll
        for (int ks = 0; ks < 2; ++ks) {
            const int k0 = ks*32 + fg*8;
            const bf16x8 aC  = *reinterpret_cast<const bf16x8*>(&sm.Cm[iw2 + fr][k0]);
            const bf16x8 aBt = *reinterpret_cast<const bf16x8*>(&sm.Bt[iw2 + fr][k0]);
            const bf16x8 bSt = *reinterpret_cast<const bf16x8*>(&sm.St16[fr][k0]);
            const bf16x8 bXt = *reinterpret_cast<const bf16x8*>(&sm.Xt[ci][fr][k0]);
            #pragma unroll
            for (int jt = 0; jt < 4; ++jt) {
                const bf16x8 bB = *reinterpret_cast<const bf16x8*>(&sm.Bm[jt*16 + fr][k0]);
                g[jt] = mfma16(aC, bB, g[jt]);
            }
            aoacc = mfma16(aC,  bSt, aoacc);
            stacc = mfma16(aBt, bXt, stacc);
        }
        if (c < 63 && wid == 0) {
            float v = aA;
            #pragma unroll
            for (int o = 1; o < 64; o <<= 1) { float t = __shfl_up(v, o, 64); if (lane >= o) v += t; }
            const float last = __shfl(v, 63, 64);
            sm.ds[nb][lane]    = expf(last - v);
            sm.dout[nb][lane]  = expf(v);
            sm.douti[nb][lane] = expf(v - last);
            if (lane == 63) sm.dlast[nb] = expf(v);
        }
        __syncthreads();   // S2

        // ---- P2: M' write, St update, stage c+1, issue loads c+2 ----
        {
            const float dl = sm.dlast[ci];
            #pragma unroll
            for (int jt = 0; jt < 4; ++jt) {
                const int j = jt*16 + fr;
                #pragma unroll
                for (int r = 0; r < 4; ++r) {
                    const int i = iw2 + fg*4 + r;
                    const float val = (i >= j) ? g[jt][r] * sm.douti[ci][i] : 0.0f;
                    sm.Mm[i][j] = (__bf16)val;
                }
            }
            #pragma unroll
            for (int r = 0; r < 4; ++r) {
                const int p = fr, n = iw2 + fg*4 + r;
                const float nv = fmaf(dl, sm.St32[p][n], stacc[r]);
                sm.St32[p][n] = nv;
                sm.St16[p][n] = (__bf16)nv;
            }
        }
        if (c < 63) {
            #pragma unroll
            for (int j = 0; j < 4; ++j) {
                *reinterpret_cast<bf16x4*>(&sm.Bm[lt0 + j][cq0]) =
                    (bf16x4){(__bf16)rbB[j][0], (__bf16)rbB[j][1], (__bf16)rbB[j][2], (__bf16)rbB[j][3]};
                *reinterpret_cast<bf16x4*>(&sm.Cm[lt0 + j][cq0]) =
                    (bf16x4){(__bf16)rbC[j][0], (__bf16)rbC[j][1], (__bf16)rbC[j][2], (__bf16)rbC[j][3]};
            }
            #pragma unroll
            for (int q = 0; q < 4; ++q)
                *reinterpret_cast<bf16x4*>(&sm.Bt[cq0 + q][lt0]) =
                    (bf16x4){(__bf16)rbB[0][q], (__bf16)rbB[1][q], (__bf16)rbB[2][q], (__bf16)rbB[3][q]};
            const float dsl = sm.ds[nb][xl];
            #pragma unroll
            for (int q = 0; q < 4; ++q) sm.Xt[nb][xp4 + q][xl] = (__bf16)(rx[q] * dsl);
        }
        if (c < 62) {
            const size_t s2 = tbase + (size_t)(c + 2)*64;
            #pragma unroll
            for (int j = 0; j < 4; ++j) {
                const size_t go = ((s2 + lt0 + j)*16 + hh)*(size_t)64 + cq0;
                *reinterpret_cast<float4*>(rbB[j]) = *reinterpret_cast<const float4*>(&Bg[go]);
                *reinterpret_cast<float4*>(rbC[j]) = *reinterpret_cast<const float4*>(&Cg[go]);
            }
            *reinterpret_cast<float4*>(rx) =
                *reinterpret_cast<const float4*>(&Xg[((s2 + xl)*16 + hh)*(size_t)64 + p0 + xp4]);
            if (wid == 0) aA = Ag[(s2 + lane)*16 + hh];
        }
        __syncthreads();   // S3

        // ---- P3: ad = M' Xs ; Y -> sY ----
        {
            f32x4 ad = {};
            #pragma unroll
            for (int ks = 0; ks < 2; ++ks) {
                const int k0 = ks*32 + fg*8;
                const bf16x8 aM = *reinterpret_cast<const bf16x8*>(&sm.Mm[iw2 + fr][k0]);
                const bf16x8 bX = *reinterpret_cast<const bf16x8*>(&sm.Xt[ci][fr][k0]);
                ad = mfma16(aM, bX, ad);
            }
            #pragma unroll
            for (int r = 0; r < 4; ++r) {
                const int i = iw2 + fg*4 + r;
                sm.sY[i][fr] = ad[r] + sm.dout[ci][i] * aoacc[r];
            }
        }
        __syncthreads();   // S4

        // ---- P4: coalesced Y store ----
        {
            const float4 v = *reinterpret_cast<const float4*>(&sm.sY[xl][xp4]);
            *reinterpret_cast<float4*>(
                &Yg[((tbase + (size_t)c*64 + xl)*16 + hh)*(size_t)64 + p0 + xp4]) = v;
        }
        // no barrier: next sY writer is P3(c+1) after S2+S3; next stage writer
        // is P2(c+1) after S2 — all waves must pass S2 first.
    }
}

extern "C" void kernel_launch(void* const* d_in, const int* in_sizes, int n_in,
                              void* d_out, int out_size, void* d_ws, size_t ws_size,
                              hipStream_t stream) {
    const float* X  = (const float*)d_in[0];
    const float* I  = (const float*)d_in[1];
    const float* A  = (const float*)d_in[2];
    const float* Bp = (const float*)d_in[3];
    const float* Cp = (const float*)d_in[4];
    float* Y = (float*)d_out;
    ssd_fused<<<dim3(4, 16, 8), 256, 0, stream>>>(X, I, A, Bp, Cp, Y);
}

// Round 11
// 172.669 us; speedup vs baseline: 1.2498x; 1.2498x over previous
//
#include <hip/hip_runtime.h>

// Mamba-2 SSD chunked scan — SINGLE fused persistent kernel (round 11).
// Structure = round 9 (best: 178us). One change: all chunk-loop barriers are
// raw "s_waitcnt lgkmcnt(0); s_barrier" instead of __syncthreads().
// WHY: __syncthreads drains vmcnt(0) -> the c+2 register prefetches issued in
// P2 were force-completed ~200cy later at S3, exposing ~900cy HBM latency
// EVERY chunk (r9: 6700cy/chunk measured vs ~1400cy of work). These barriers
// only need LDS visibility: every global load is consumed by the thread that
// issued it (compiler inserts per-value vmcnt waits at the use). r10's
// p-quarter split regressed (FETCH 672MB: 4x redundant B/C staging) - reverted.

typedef __bf16 bf16x4 __attribute__((ext_vector_type(4)));
typedef __bf16 bf16x8 __attribute__((ext_vector_type(8)));
typedef float  f32x4  __attribute__((ext_vector_type(4)));

constexpr int LDT = 72;   // bf16 row stride (144 B)

__device__ __forceinline__ f32x4 mfma16(bf16x8 a, bf16x8 b, f32x4 c) {
    return __builtin_amdgcn_mfma_f32_16x16x32_bf16(a, b, c, 0, 0, 0);
}

// LDS-only barrier: waits LDS ops of THIS wave, then syncs workgroup.
// Does NOT drain vmcnt — in-flight global register-prefetches survive.
__device__ __forceinline__ void bar_lds() {
    asm volatile("s_waitcnt lgkmcnt(0)\n\ts_barrier" ::: "memory");
}

struct SMemF {
    __bf16 Cm[64][LDT];      // C row-major [l][n]
    __bf16 Bm[64][LDT];      // B row-major [l][n]
    __bf16 Bt[64][LDT];      // B^T [n][l]
    __bf16 Mm[64][LDT];      // M' [i][j]
    __bf16 Xt[2][32][LDT];   // Xs^T [p][l], double-buffered
    __bf16 St16[32][LDT];    // state bf16 (operand copy)
    float  St32[32][68];     // state f32 (master)
    float  sY[64][36];       // Y staging (p-half)
    float  ds[2][64];        // e^{cs63-cs_l}
    float  dout[2][64];      // e^{cs_i}
    float  douti[2][64];     // e^{cs_i-cs63}
    float  dlast[2];         // e^{cs63}
};

__global__ void ssd_fused(const float* __restrict__ Xg, const float* __restrict__ Ig,
                          const float* __restrict__ Ag, const float* __restrict__ Bg,
                          const float* __restrict__ Cg, float* __restrict__ Yg)
{
    const int ph = blockIdx.x, hh = blockIdx.y, bb = blockIdx.z;
    const int tid = threadIdx.x;            // 0..511
    const int wid = tid >> 6, lane = tid & 63;
    const int fr = lane & 15, fg = lane >> 4;
    const int iw2 = (wid >> 1) * 16;        // i-strip (also st n-strip)
    const int pt  = (wid & 1) * 16;         // p-tile
    const int jh  = (wid & 1) * 32;         // G j-half base

    __shared__ __align__(16) SMemF sm;
    const size_t tbase = (size_t)bb * 4096;

    // staging role split
    const int half = tid >> 8;              // 0: B rows (flat+transpose), 1: C rows
    const int u    = tid & 255;
    const int lt0  = (u >> 4) * 4;          // B: 4-row block
    const int rr0  = u >> 4;                // C: base row
    const int cq0  = (u & 15) * 4;          // column quad
    // X / Y map
    const int xl  = tid >> 3;               // 0..63
    const int xp4 = (tid & 7) * 4;          // 0..28
    // St init map
    const int sp  = tid >> 4;               // 0..31
    const int sn4 = (tid & 15) * 4;

    float rb[4][4];   // B or C rows (per role)
    float rx[4];      // X row segment
    float aA = 0.0f;  // wave0: A value for next scan

    // ---------------- prologue ----------------
    // initial state
    {
        const size_t iofs = (((size_t)bb*16 + hh)*64 + (ph*32 + sp))*(size_t)64 + sn4;
        const float4 v = *reinterpret_cast<const float4*>(&Ig[iofs]);
        sm.St32[sp][sn4+0] = v.x; sm.St32[sp][sn4+1] = v.y;
        sm.St32[sp][sn4+2] = v.z; sm.St32[sp][sn4+3] = v.w;
        *reinterpret_cast<bf16x4*>(&sm.St16[sp][sn4]) =
            (bf16x4){(__bf16)v.x, (__bf16)v.y, (__bf16)v.z, (__bf16)v.w};
    }
    // chunk-0 loads
    #pragma unroll
    for (int j = 0; j < 4; ++j) {
        const int row = (half == 0) ? (lt0 + j) : (rr0 + 16*j);
        const size_t go = ((tbase + row)*16 + hh)*(size_t)64 + cq0;
        *reinterpret_cast<float4*>(rb[j]) = (half == 0)
            ? *reinterpret_cast<const float4*>(&Bg[go])
            : *reinterpret_cast<const float4*>(&Cg[go]);
    }
    *reinterpret_cast<float4*>(rx) =
        *reinterpret_cast<const float4*>(&Xg[((tbase + xl)*16 + hh)*(size_t)64 + ph*32 + xp4]);
    if (wid == 0) aA = Ag[(tbase + lane)*16 + hh];

    // scan chunk 0 -> tables[0]
    if (wid == 0) {
        float v = aA;
        #pragma unroll
        for (int o = 1; o < 64; o <<= 1) { float t = __shfl_up(v, o, 64); if (lane >= o) v += t; }
        const float last = __shfl(v, 63, 64);
        sm.ds[0][lane]    = expf(last - v);
        sm.dout[0][lane]  = expf(v);
        sm.douti[0][lane] = expf(v - last);
        if (lane == 63) sm.dlast[0] = expf(v);
    }
    // stage chunk-0 C/B/Bt (no table dependency)
    if (half == 0) {
        #pragma unroll
        for (int j = 0; j < 4; ++j)
            *reinterpret_cast<bf16x4*>(&sm.Bm[lt0 + j][cq0]) =
                (bf16x4){(__bf16)rb[j][0], (__bf16)rb[j][1], (__bf16)rb[j][2], (__bf16)rb[j][3]};
        #pragma unroll
        for (int q = 0; q < 4; ++q)
            *reinterpret_cast<bf16x4*>(&sm.Bt[cq0 + q][lt0]) =
                (bf16x4){(__bf16)rb[0][q], (__bf16)rb[1][q], (__bf16)rb[2][q], (__bf16)rb[3][q]};
    } else {
        #pragma unroll
        for (int j = 0; j < 4; ++j)
            *reinterpret_cast<bf16x4*>(&sm.Cm[rr0 + 16*j][cq0]) =
                (bf16x4){(__bf16)rb[j][0], (__bf16)rb[j][1], (__bf16)rb[j][2], (__bf16)rb[j][3]};
    }
    bar_lds();   // tables[0] + St ready
    // stage Xs^T[0] (needs ds[0])
    {
        const float dsl = sm.ds[0][xl];
        #pragma unroll
        for (int q = 0; q < 4; ++q) sm.Xt[0][xp4 + q][xl] = (__bf16)(rx[q] * dsl);
    }
    // chunk-1 loads
    #pragma unroll
    for (int j = 0; j < 4; ++j) {
        const int row = (half == 0) ? (lt0 + j) : (rr0 + 16*j);
        const size_t go = ((tbase + 64 + row)*16 + hh)*(size_t)64 + cq0;
        *reinterpret_cast<float4*>(rb[j]) = (half == 0)
            ? *reinterpret_cast<const float4*>(&Bg[go])
            : *reinterpret_cast<const float4*>(&Cg[go]);
    }
    *reinterpret_cast<float4*>(rx) =
        *reinterpret_cast<const float4*>(&Xg[((tbase + 64 + xl)*16 + hh)*(size_t)64 + ph*32 + xp4]);
    if (wid == 0) aA = Ag[(tbase + 64 + lane)*16 + hh];
    bar_lds();   // Xt[0] visible

    // ---------------- chunk loop ----------------
    for (int c = 0; c < 64; ++c) {
        const int ci = c & 1, nb = (c + 1) & 1;

        // ---- P1: MFMAs for chunk c (+ wave0 scans c+1) ----
        f32x4 g0 = {}, g1 = {}, aoacc = {}, stacc = {};
        #pragma unroll
        for (int ks = 0; ks < 2; ++ks) {
            const int k0 = ks*32 + fg*8;
            const bf16x8 aC  = *reinterpret_cast<const bf16x8*>(&sm.Cm[iw2 + fr][k0]);
            const bf16x8 bB0 = *reinterpret_cast<const bf16x8*>(&sm.Bm[jh      + fr][k0]);
            const bf16x8 bB1 = *reinterpret_cast<const bf16x8*>(&sm.Bm[jh + 16 + fr][k0]);
            const bf16x8 bSt = *reinterpret_cast<const bf16x8*>(&sm.St16[pt + fr][k0]);
            const bf16x8 aBt = *reinterpret_cast<const bf16x8*>(&sm.Bt[iw2 + fr][k0]);
            const bf16x8 bXt = *reinterpret_cast<const bf16x8*>(&sm.Xt[ci][pt + fr][k0]);
            g0    = mfma16(aC,  bB0, g0);
            g1    = mfma16(aC,  bB1, g1);
            aoacc = mfma16(aC,  bSt, aoacc);
            stacc = mfma16(aBt, bXt, stacc);
        }
        if (c < 63 && wid == 0) {
            float v = aA;
            #pragma unroll
            for (int o = 1; o < 64; o <<= 1) { float t = __shfl_up(v, o, 64); if (lane >= o) v += t; }
            const float last = __shfl(v, 63, 64);
            sm.ds[nb][lane]    = expf(last - v);
            sm.dout[nb][lane]  = expf(v);
            sm.douti[nb][lane] = expf(v - last);
            if (lane == 63) sm.dlast[nb] = expf(v);
        }
        bar_lds();   // S2

        // ---- P2: M' write, St update, stage c+1, issue loads c+2 ----
        {
            const float dl = sm.dlast[ci];
            #pragma unroll
            for (int jt = 0; jt < 2; ++jt) {
                const int j = jh + jt*16 + fr;
                const f32x4& gg = jt ? g1 : g0;
                #pragma unroll
                for (int r = 0; r < 4; ++r) {
                    const int i = iw2 + fg*4 + r;
                    const float val = (i >= j) ? gg[r] * sm.douti[ci][i] : 0.0f;
                    sm.Mm[i][j] = (__bf16)val;
                }
            }
            #pragma unroll
            for (int r = 0; r < 4; ++r) {
                const int p = pt + fr, n = iw2 + fg*4 + r;
                const float nv = fmaf(dl, sm.St32[p][n], stacc[r]);
                sm.St32[p][n] = nv;
                sm.St16[p][n] = (__bf16)nv;
            }
        }
        if (c < 63) {
            if (half == 0) {
                #pragma unroll
                for (int j = 0; j < 4; ++j)
                    *reinterpret_cast<bf16x4*>(&sm.Bm[lt0 + j][cq0]) =
                        (bf16x4){(__bf16)rb[j][0], (__bf16)rb[j][1], (__bf16)rb[j][2], (__bf16)rb[j][3]};
                #pragma unroll
                for (int q = 0; q < 4; ++q)
                    *reinterpret_cast<bf16x4*>(&sm.Bt[cq0 + q][lt0]) =
                        (bf16x4){(__bf16)rb[0][q], (__bf16)rb[1][q], (__bf16)rb[2][q], (__bf16)rb[3][q]};
            } else {
                #pragma unroll
                for (int j = 0; j < 4; ++j)
                    *reinterpret_cast<bf16x4*>(&sm.Cm[rr0 + 16*j][cq0]) =
                        (bf16x4){(__bf16)rb[j][0], (__bf16)rb[j][1], (__bf16)rb[j][2], (__bf16)rb[j][3]};
            }
            const float dsl = sm.ds[nb][xl];
            #pragma unroll
            for (int q = 0; q < 4; ++q) sm.Xt[nb][xp4 + q][xl] = (__bf16)(rx[q] * dsl);
        }
        if (c < 62) {
            const size_t s2 = tbase + (size_t)(c + 2)*64;
            #pragma unroll
            for (int j = 0; j < 4; ++j) {
                const int row = (half == 0) ? (lt0 + j) : (rr0 + 16*j);
                const size_t go = ((s2 + row)*16 + hh)*(size_t)64 + cq0;
                *reinterpret_cast<float4*>(rb[j]) = (half == 0)
                    ? *reinterpret_cast<const float4*>(&Bg[go])
                    : *reinterpret_cast<const float4*>(&Cg[go]);
            }
            *reinterpret_cast<float4*>(rx) =
                *reinterpret_cast<const float4*>(&Xg[((s2 + xl)*16 + hh)*(size_t)64 + ph*32 + xp4]);
            if (wid == 0) aA = Ag[(s2 + lane)*16 + hh];
        }
        bar_lds();   // S3 — prefetches stay in flight across this barrier

        // ---- P3: ad = M' Xs ; Y -> sY ----
        {
            f32x4 ad = {};
            #pragma unroll
            for (int ks = 0; ks < 2; ++ks) {
                const int k0 = ks*32 + fg*8;
                const bf16x8 aM = *reinterpret_cast<const bf16x8*>(&sm.Mm[iw2 + fr][k0]);
                const bf16x8 bX = *reinterpret_cast<const bf16x8*>(&sm.Xt[ci][pt + fr][k0]);
                ad = mfma16(aM, bX, ad);
            }
            #pragma unroll
            for (int r = 0; r < 4; ++r) {
                const int i = iw2 + fg*4 + r;
                sm.sY[i][pt + fr] = ad[r] + sm.dout[ci][i] * aoacc[r];
            }
        }
        bar_lds();   // S4

        // ---- P4: coalesced Y store ----
        {
            const float4 v = *reinterpret_cast<const float4*>(&sm.sY[xl][xp4]);
            *reinterpret_cast<float4*>(
                &Yg[((tbase + (size_t)c*64 + xl)*16 + hh)*(size_t)64 + ph*32 + xp4]) = v;
        }
        // no barrier needed here: next writer of sY is P3(c+1), after S2+S3;
        // each wave's sY ds_read completes before it crosses S2 (lgkmcnt(0)).
    }
}

extern "C" void kernel_launch(void* const* d_in, const int* in_sizes, int n_in,
                              void* d_out, int out_size, void* d_ws, size_t ws_size,
                              hipStream_t stream) {
    const float* X  = (const float*)d_in[0];
    const float* I  = (const float*)d_in[1];
    const float* A  = (const float*)d_in[2];
    const float* Bp = (const float*)d_in[3];
    const float* Cp = (const float*)d_in[4];
    float* Y = (float*)d_out;
    ssd_fused<<<dim3(2, 16, 8), 512, 0, stream>>>(X, I, A, Bp, Cp, Y);
}

// Round 12
// 146.101 us; speedup vs baseline: 1.4771x; 1.1818x over previous
//
#include <hip/hip_runtime.h>

// Mamba-2 SSD chunked scan — fused persistent kernel (round 12).
// Skeleton = r9/r11 (block = (p-half,h,b), 256 blocks x 512 thr, LDS state).
// Round-12: (a) 2 phases/chunk instead of 4 — ad(c-1)=M'*Xs moved into phase
// A(c) so all 10 MFMA + 16 ds_reads issue together (ILP); Y(c-1) stored in
// B(c); tables triple-buffered to survive the 1-chunk lag. (b) XOR swizzle
// (byte ^= ((row>>2)&7)<<4) on the two TRANSPOSED LDS buffers (Bt, Xt) whose
// column-writes were 8-16-way bank conflicts (2.05e7 cycles = ~19% of r11).
// Barriers: lgkmcnt-only (r11, vmcnt stays in flight). Canaries: WRITE_SIZE
// == 131072 KB exactly (no spill/no write-amp); absmax <= 1.
// r10 lesson kept: no p-quarter split (4x B/C staging -> FETCH 672MB).

typedef __bf16 bf16x4 __attribute__((ext_vector_type(4)));
typedef __bf16 bf16x8 __attribute__((ext_vector_type(8)));
typedef float  f32x4  __attribute__((ext_vector_type(4)));

constexpr int LDT = 72;   // bf16 row stride (144 B)

__device__ __forceinline__ f32x4 mfma16(bf16x8 a, bf16x8 b, f32x4 c) {
    return __builtin_amdgcn_mfma_f32_16x16x32_bf16(a, b, c, 0, 0, 0);
}
// LDS-only barrier: does NOT drain vmcnt (global reg-prefetches stay in flight)
__device__ __forceinline__ void bar_lds() {
    asm volatile("s_waitcnt lgkmcnt(0)\n\ts_barrier" ::: "memory");
}
// 8B-unit XOR swizzle for transposed buffers; preserves 8B/16B alignment
// (only byte-bits >=4 change). Same map on write and read.
__device__ __forceinline__ int swz(int row, int byteoff) {
    return byteoff ^ (((row >> 2) & 7) << 4);
}

struct SMemF {
    __bf16 Cm[64][LDT];      // C row-major [l][n]
    __bf16 Bm[64][LDT];      // B row-major [l][n]
    __bf16 Bt[64][LDT];      // B^T [n][l]   (XOR-swizzled)
    __bf16 Mm[64][LDT];      // M' [i][j]
    __bf16 Xt[2][32][LDT];   // Xs^T [p][l]  (XOR-swizzled, double-buffered)
    __bf16 St16[32][LDT];    // state bf16 (operand copy)
    float  St32[32][68];     // state f32 (master)
    float  sY[64][36];       // Y staging (p-half)
    float  ds[3][64];        // e^{cs63-cs_l}   } triple-buffered:
    float  dout[3][64];      // e^{cs_i}        } scan(c+1) runs in A(c) while
    float  douti[3][64];     // e^{cs_i-cs63}   } chunk c-1 tables still read
    float  dlast[3];         // e^{cs63}
};

__global__ void ssd_fused(const float* __restrict__ Xg, const float* __restrict__ Ig,
                          const float* __restrict__ Ag, const float* __restrict__ Bg,
                          const float* __restrict__ Cg, float* __restrict__ Yg)
{
    const int ph = blockIdx.x, hh = blockIdx.y, bb = blockIdx.z;
    const int tid = threadIdx.x;            // 0..511
    const int wid = tid >> 6, lane = tid & 63;
    const int fr = lane & 15, fg = lane >> 4;
    const int iw2 = (wid >> 1) * 16;        // i-strip / n-strip
    const int pt  = (wid & 1) * 16;         // p-tile
    const int jh  = (wid & 1) * 32;         // G j-half base

    __shared__ __align__(16) SMemF sm;
    const size_t tbase = (size_t)bb * 4096;

    // staging role split
    const int half = tid >> 8;              // 0: B rows (+transpose), 1: C rows
    const int u    = tid & 255;
    const int lt0  = (u >> 4) * 4;
    const int rr0  = u >> 4;
    const int cq0  = (u & 15) * 4;
    const int xl  = tid >> 3;               // X/Y row 0..63
    const int xp4 = (tid & 7) * 4;          // X/Y p quad
    const int sp  = tid >> 4;               // St row 0..31
    const int sn4 = (tid & 15) * 4;

    float rb[4][4], rx[4];
    float aA = 0.0f;

    // ---------------- prologue ----------------
    {
        const size_t iofs = (((size_t)bb*16 + hh)*64 + (ph*32 + sp))*(size_t)64 + sn4;
        const float4 v = *reinterpret_cast<const float4*>(&Ig[iofs]);
        sm.St32[sp][sn4+0] = v.x; sm.St32[sp][sn4+1] = v.y;
        sm.St32[sp][sn4+2] = v.z; sm.St32[sp][sn4+3] = v.w;
        *reinterpret_cast<bf16x4*>(&sm.St16[sp][sn4]) =
            (bf16x4){(__bf16)v.x, (__bf16)v.y, (__bf16)v.z, (__bf16)v.w};
    }
    #pragma unroll
    for (int j = 0; j < 4; ++j) {
        const int row = (half == 0) ? (lt0 + j) : (rr0 + 16*j);
        const size_t go = ((tbase + row)*16 + hh)*(size_t)64 + cq0;
        *reinterpret_cast<float4*>(rb[j]) = (half == 0)
            ? *reinterpret_cast<const float4*>(&Bg[go])
            : *reinterpret_cast<const float4*>(&Cg[go]);
    }
    *reinterpret_cast<float4*>(rx) =
        *reinterpret_cast<const float4*>(&Xg[((tbase + xl)*16 + hh)*(size_t)64 + ph*32 + xp4]);
    if (wid == 0) aA = Ag[(tbase + lane)*16 + hh];

    if (wid == 0) {   // scan chunk 0 -> tables[0]
        float v = aA;
        #pragma unroll
        for (int o = 1; o < 64; o <<= 1) { float t = __shfl_up(v, o, 64); if (lane >= o) v += t; }
        const float last = __shfl(v, 63, 64);
        sm.ds[0][lane]    = expf(last - v);
        sm.dout[0][lane]  = expf(v);
        sm.douti[0][lane] = expf(v - last);
        if (lane == 63) sm.dlast[0] = expf(v);
    }
    // stage chunk-0 C/B/Bt
    if (half == 0) {
        #pragma unroll
        for (int j = 0; j < 4; ++j)
            *reinterpret_cast<bf16x4*>(&sm.Bm[lt0 + j][cq0]) =
                (bf16x4){(__bf16)rb[j][0], (__bf16)rb[j][1], (__bf16)rb[j][2], (__bf16)rb[j][3]};
        #pragma unroll
        for (int q = 0; q < 4; ++q)
            *reinterpret_cast<bf16x4*>(
                reinterpret_cast<char*>(&sm.Bt[cq0 + q][0]) + swz(cq0 + q, lt0*2)) =
                (bf16x4){(__bf16)rb[0][q], (__bf16)rb[1][q], (__bf16)rb[2][q], (__bf16)rb[3][q]};
    } else {
        #pragma unroll
        for (int j = 0; j < 4; ++j)
            *reinterpret_cast<bf16x4*>(&sm.Cm[rr0 + 16*j][cq0]) =
                (bf16x4){(__bf16)rb[j][0], (__bf16)rb[j][1], (__bf16)rb[j][2], (__bf16)rb[j][3]};
    }
    bar_lds();
    {   // stage Xt[0] (needs ds[0]); swizzled scalar writes
        const float dsl = sm.ds[0][xl];
        #pragma unroll
        for (int q = 0; q < 4; ++q)
            *reinterpret_cast<__bf16*>(
                reinterpret_cast<char*>(&sm.Xt[0][xp4 + q][0]) + swz(xp4 + q, xl*2)) =
                (__bf16)(rx[q] * dsl);
    }
    #pragma unroll
    for (int j = 0; j < 4; ++j) {   // chunk-1 loads
        const int row = (half == 0) ? (lt0 + j) : (rr0 + 16*j);
        const size_t go = ((tbase + 64 + row)*16 + hh)*(size_t)64 + cq0;
        *reinterpret_cast<float4*>(rb[j]) = (half == 0)
            ? *reinterpret_cast<const float4*>(&Bg[go])
            : *reinterpret_cast<const float4*>(&Cg[go]);
    }
    *reinterpret_cast<float4*>(rx) =
        *reinterpret_cast<const float4*>(&Xg[((tbase + 64 + xl)*16 + hh)*(size_t)64 + ph*32 + xp4]);
    if (wid == 0) aA = Ag[(tbase + 64 + lane)*16 + hh];
    bar_lds();

    f32x4 aoprev = {};
    int t0 = 0, t1 = 1, t2 = 2;   // t0 = c%3, t1 = (c+1)%3, t2 = (c-1)%3

    // ---------------- chunk loop: 2 phases, 2 barriers ----------------
    for (int c = 0; c < 64; ++c) {
        const int ci = c & 1, nb = ci ^ 1;

        // ==== Phase A: all MFMAs (chunk c: g/ao/st; chunk c-1: ad) + scan(c+1) ====
        f32x4 g0 = {}, g1 = {}, aoacc = {}, stacc = {};
        #pragma unroll
        for (int ks = 0; ks < 2; ++ks) {
            const int k0 = ks*32 + fg*8;
            const bf16x8 aC  = *reinterpret_cast<const bf16x8*>(&sm.Cm[iw2 + fr][k0]);
            const bf16x8 bB0 = *reinterpret_cast<const bf16x8*>(&sm.Bm[jh      + fr][k0]);
            const bf16x8 bB1 = *reinterpret_cast<const bf16x8*>(&sm.Bm[jh + 16 + fr][k0]);
            const bf16x8 bSt = *reinterpret_cast<const bf16x8*>(&sm.St16[pt + fr][k0]);
            const bf16x8 aBt = *reinterpret_cast<const bf16x8*>(
                reinterpret_cast<const char*>(&sm.Bt[iw2 + fr][0]) + swz(iw2 + fr, k0*2));
            const bf16x8 bXt = *reinterpret_cast<const bf16x8*>(
                reinterpret_cast<const char*>(&sm.Xt[ci][pt + fr][0]) + swz(pt + fr, k0*2));
            g0    = mfma16(aC,  bB0, g0);
            g1    = mfma16(aC,  bB1, g1);
            aoacc = mfma16(aC,  bSt, aoacc);
            stacc = mfma16(aBt, bXt, stacc);
        }
        if (c > 0) {   // ad(c-1) = M'(c-1) @ Xs(c-1); sY(c-1) = ad + dout*aoprev
            f32x4 ad = {};
            #pragma unroll
            for (int ks = 0; ks < 2; ++ks) {
                const int k0 = ks*32 + fg*8;
                const bf16x8 aM = *reinterpret_cast<const bf16x8*>(&sm.Mm[iw2 + fr][k0]);
                const bf16x8 bX = *reinterpret_cast<const bf16x8*>(
                    reinterpret_cast<const char*>(&sm.Xt[nb][pt + fr][0]) + swz(pt + fr, k0*2));
                ad = mfma16(aM, bX, ad);
            }
            #pragma unroll
            for (int r = 0; r < 4; ++r) {
                const int i = iw2 + fg*4 + r;
                sm.sY[i][pt + fr] = ad[r] + sm.dout[t2][i] * aoprev[r];
            }
        }
        if (c < 63 && wid == 0) {   // scan chunk c+1 -> tables[t1]
            float v = aA;
            #pragma unroll
            for (int o = 1; o < 64; o <<= 1) { float t = __shfl_up(v, o, 64); if (lane >= o) v += t; }
            const float last = __shfl(v, 63, 64);
            sm.ds[t1][lane]    = expf(last - v);
            sm.dout[t1][lane]  = expf(v);
            sm.douti[t1][lane] = expf(v - last);
            if (lane == 63) sm.dlast[t1] = expf(v);
        }
        aoprev = aoacc;
        bar_lds();   // S_A

        // ==== Phase B: Y store(c-1); M'(c); St update; stage(c+1); prefetch(c+2) ====
        if (c > 0) {
            const float4 v = *reinterpret_cast<const float4*>(&sm.sY[xl][xp4]);
            *reinterpret_cast<float4*>(
                &Yg[((tbase + (size_t)(c-1)*64 + xl)*16 + hh)*(size_t)64 + ph*32 + xp4]) = v;
        }
        {   // M' = mask(G) * e^{cs_i - cs63}
            #pragma unroll
            for (int jt = 0; jt < 2; ++jt) {
                const int j = jh + jt*16 + fr;
                const f32x4& gg = jt ? g1 : g0;
                #pragma unroll
                for (int r = 0; r < 4; ++r) {
                    const int i = iw2 + fg*4 + r;
                    const float val = (i >= j) ? gg[r] * sm.douti[t0][i] : 0.0f;
                    sm.Mm[i][j] = (__bf16)val;
                }
            }
        }
        {   // St = e^{cs63} * St + stch   (vectorized: n0..n0+3 contiguous)
            const float dl = sm.dlast[t0];
            const int p = pt + fr, n0 = iw2 + fg*4;
            const float4 ov = *reinterpret_cast<const float4*>(&sm.St32[p][n0]);
            float4 nv;
            nv.x = fmaf(dl, ov.x, stacc[0]); nv.y = fmaf(dl, ov.y, stacc[1]);
            nv.z = fmaf(dl, ov.z, stacc[2]); nv.w = fmaf(dl, ov.w, stacc[3]);
            *reinterpret_cast<float4*>(&sm.St32[p][n0]) = nv;
            *reinterpret_cast<bf16x4*>(&sm.St16[p][n0]) =
                (bf16x4){(__bf16)nv.x, (__bf16)nv.y, (__bf16)nv.z, (__bf16)nv.w};
        }
        if (c < 63) {   // stage chunk c+1 from regs
            if (half == 0) {
                #pragma unroll
                for (int j = 0; j < 4; ++j)
                    *reinterpret_cast<bf16x4*>(&sm.Bm[lt0 + j][cq0]) =
                        (bf16x4){(__bf16)rb[j][0], (__bf16)rb[j][1], (__bf16)rb[j][2], (__bf16)rb[j][3]};
                #pragma unroll
                for (int q = 0; q < 4; ++q)
                    *reinterpret_cast<bf16x4*>(
                        reinterpret_cast<char*>(&sm.Bt[cq0 + q][0]) + swz(cq0 + q, lt0*2)) =
                        (bf16x4){(__bf16)rb[0][q], (__bf16)rb[1][q], (__bf16)rb[2][q], (__bf16)rb[3][q]};
            } else {
                #pragma unroll
                for (int j = 0; j < 4; ++j)
                    *reinterpret_cast<bf16x4*>(&sm.Cm[rr0 + 16*j][cq0]) =
                        (bf16x4){(__bf16)rb[j][0], (__bf16)rb[j][1], (__bf16)rb[j][2], (__bf16)rb[j][3]};
            }
            const float dsl = sm.ds[t1][xl];
            #pragma unroll
            for (int q = 0; q < 4; ++q)
                *reinterpret_cast<__bf16*>(
                    reinterpret_cast<char*>(&sm.Xt[nb][xp4 + q][0]) + swz(xp4 + q, xl*2)) =
                    (__bf16)(rx[q] * dsl);
        }
        if (c < 62) {   // issue loads for chunk c+2 (consumed next B — ~2 phases of cover)
            const size_t s2 = tbase + (size_t)(c + 2)*64;
            #pragma unroll
            for (int j = 0; j < 4; ++j) {
                const int row = (half == 0) ? (lt0 + j) : (rr0 + 16*j);
                const size_t go = ((s2 + row)*16 + hh)*(size_t)64 + cq0;
                *reinterpret_cast<float4*>(rb[j]) = (half == 0)
                    ? *reinterpret_cast<const float4*>(&Bg[go])
                    : *reinterpret_cast<const float4*>(&Cg[go]);
            }
            *reinterpret_cast<float4*>(rx) =
                *reinterpret_cast<const float4*>(&Xg[((s2 + xl)*16 + hh)*(size_t)64 + ph*32 + xp4]);
            if (wid == 0) aA = Ag[(s2 + lane)*16 + hh];
        }
        bar_lds();   // S_B

        const int tt = t0; t0 = t1; t1 = t2; t2 = tt;   // rotate table buffers
    }

    // ---------------- epilogue: chunk 63's diag part + store ----------------
    {
        f32x4 ad = {};
        #pragma unroll
        for (int ks = 0; ks < 2; ++ks) {
            const int k0 = ks*32 + fg*8;
            const bf16x8 aM = *reinterpret_cast<const bf16x8*>(&sm.Mm[iw2 + fr][k0]);
            const bf16x8 bX = *reinterpret_cast<const bf16x8*>(
                reinterpret_cast<const char*>(&sm.Xt[1][pt + fr][0]) + swz(pt + fr, k0*2));
            ad = mfma16(aM, bX, ad);
        }
        #pragma unroll
        for (int r = 0; r < 4; ++r) {
            const int i = iw2 + fg*4 + r;
            sm.sY[i][pt + fr] = ad[r] + sm.dout[t2][i] * aoprev[r];
        }
    }
    bar_lds();
    {
        const float4 v = *reinterpret_cast<const float4*>(&sm.sY[xl][xp4]);
        *reinterpret_cast<float4*>(
            &Yg[((tbase + (size_t)63*64 + xl)*16 + hh)*(size_t)64 + ph*32 + xp4]) = v;
    }
}

extern "C" void kernel_launch(void* const* d_in, const int* in_sizes, int n_in,
                              void* d_out, int out_size, void* d_ws, size_t ws_size,
                              hipStream_t stream) {
    const float* X  = (const float*)d_in[0];
    const float* I  = (const float*)d_in[1];
    const float* A  = (const float*)d_in[2];
    const float* Bp = (const float*)d_in[3];
    const float* Cp = (const float*)d_in[4];
    float* Y = (float*)d_out;
    ssd_fused<<<dim3(2, 16, 8), 512, 0, stream>>>(X, I, A, Bp, Cp, Y);
}

// Round 13
// 131.534 us; speedup vs baseline: 1.6407x; 1.1107x over previous
//
#include <hip/hip_runtime.h>

// Mamba-2 SSD chunked scan — fused persistent kernel (round 13).
// Skeleton = r12 (block=(p-half,h,b), 256x512, LDS state, lgkm-only barriers,
// XOR swizzle on Bt/Xt). Round-13: ONE barrier per chunk (r12 had 2; r11 4).
// All same-phase hazards removed by buffering:
//   Cm/Bm/Bt/Mm/St16/sY double-buffered (parity ci), Xt TRIPLE-buffered
//   (phase c reads Xt[c%3] for st-MFMA, Xt[(c-1)%3] for ad, writes Xt[(c+1)%3]),
//   decay tables QUAD-buffered with scan TWO ahead (scan(c+2) in phase c, so
//   staging's ds[c+1] read never races a same-phase scan write).
// Phase c: MFMA{g,ao,st}(c) + ad(c-1) | scan(c+2) | Y-store(c-2) | stage(c+1)
//          | prefetch(c+2) | sY(c-1)/M'(c)/St(c) writes | bar_lds.
// Epilogue drains Y(62), Y(63). LDS ~124KB (fits 160K; grid=256=1 blk/CU by
// construction so LDS is free). Canaries: WRITE_SIZE==131072 KB, absmax<=1.

typedef __bf16 bf16x4 __attribute__((ext_vector_type(4)));
typedef __bf16 bf16x8 __attribute__((ext_vector_type(8)));
typedef float  f32x4  __attribute__((ext_vector_type(4)));

constexpr int LDT = 72;   // bf16 row stride (144 B)

__device__ __forceinline__ f32x4 mfma16(bf16x8 a, bf16x8 b, f32x4 c) {
    return __builtin_amdgcn_mfma_f32_16x16x32_bf16(a, b, c, 0, 0, 0);
}
// LDS-only barrier: does NOT drain vmcnt (global reg-prefetches stay in flight)
__device__ __forceinline__ void bar_lds() {
    asm volatile("s_waitcnt lgkmcnt(0)\n\ts_barrier" ::: "memory");
}
// XOR swizzle for transposed buffers (16B granularity, rows grouped by 4)
__device__ __forceinline__ int swz(int row, int byteoff) {
    return byteoff ^ (((row >> 2) & 7) << 4);
}

struct SMemF {
    __bf16 Cm[2][64][LDT];   // C row-major [l][n]
    __bf16 Bm[2][64][LDT];   // B row-major [l][n]
    __bf16 Bt[2][64][LDT];   // B^T [n][l] (swizzled)
    __bf16 Mm[2][64][LDT];   // M' [i][j]
    __bf16 Xt[3][32][LDT];   // Xs^T [p][l] (swizzled, TRIPLE)
    __bf16 St16[2][32][LDT]; // state bf16 operand copy (parity)
    float  St32[32][68];     // state f32 master (per-lane exclusive)
    float  sY[2][64][36];    // Y staging (parity)
    float  ds[4][64];        // e^{cs63-cs_l}   } quad-buffered (c%4):
    float  dout[4][64];      // e^{cs_i}        } scan(c+2) writes (c+2)%4 while
    float  douti[4][64];     // e^{cs_i-cs63}   } c,c+1,c-1 still being read
    float  dlast[4];         // e^{cs63}
};

__global__ void ssd_fused(const float* __restrict__ Xg, const float* __restrict__ Ig,
                          const float* __restrict__ Ag, const float* __restrict__ Bg,
                          const float* __restrict__ Cg, float* __restrict__ Yg)
{
    const int ph = blockIdx.x, hh = blockIdx.y, bb = blockIdx.z;
    const int tid = threadIdx.x;            // 0..511
    const int wid = tid >> 6, lane = tid & 63;
    const int fr = lane & 15, fg = lane >> 4;
    const int iw2 = (wid >> 1) * 16;        // i-strip / n-strip
    const int pt  = (wid & 1) * 16;         // p-tile
    const int jh  = (wid & 1) * 32;         // G j-half base

    __shared__ __align__(16) SMemF sm;
    const size_t tbase = (size_t)bb * 4096;

    const int half = tid >> 8;              // 0: B rows (+transpose), 1: C rows
    const int u    = tid & 255;
    const int lt0  = (u >> 4) * 4;
    const int rr0  = u >> 4;
    const int cq0  = (u & 15) * 4;
    const int xl  = tid >> 3;               // X/Y row 0..63
    const int xp4 = (tid & 7) * 4;          // X/Y p quad
    const int sp  = tid >> 4;               // St row 0..31
    const int sn4 = (tid & 15) * 4;

    float rb[4][4], rx[4];
    float aA = 0.0f;

    auto scan_to = [&](float v, int tb) {
        #pragma unroll
        for (int o = 1; o < 64; o <<= 1) { float t = __shfl_up(v, o, 64); if (lane >= o) v += t; }
        const float last = __shfl(v, 63, 64);
        sm.ds[tb][lane]    = expf(last - v);
        sm.dout[tb][lane]  = expf(v);
        sm.douti[tb][lane] = expf(v - last);
        if (lane == 63) sm.dlast[tb] = expf(v);
    };

    // ---------------- prologue ----------------
    {   // initial state -> St32 + St16[0]
        const size_t iofs = (((size_t)bb*16 + hh)*64 + (ph*32 + sp))*(size_t)64 + sn4;
        const float4 v = *reinterpret_cast<const float4*>(&Ig[iofs]);
        sm.St32[sp][sn4+0] = v.x; sm.St32[sp][sn4+1] = v.y;
        sm.St32[sp][sn4+2] = v.z; sm.St32[sp][sn4+3] = v.w;
        *reinterpret_cast<bf16x4*>(&sm.St16[0][sp][sn4]) =
            (bf16x4){(__bf16)v.x, (__bf16)v.y, (__bf16)v.z, (__bf16)v.w};
    }
    // chunk-0 loads
    #pragma unroll
    for (int j = 0; j < 4; ++j) {
        const int row = (half == 0) ? (lt0 + j) : (rr0 + 16*j);
        const size_t go = ((tbase + row)*16 + hh)*(size_t)64 + cq0;
        *reinterpret_cast<float4*>(rb[j]) = (half == 0)
            ? *reinterpret_cast<const float4*>(&Bg[go])
            : *reinterpret_cast<const float4*>(&Cg[go]);
    }
    *reinterpret_cast<float4*>(rx) =
        *reinterpret_cast<const float4*>(&Xg[((tbase + xl)*16 + hh)*(size_t)64 + ph*32 + xp4]);
    // scans for chunks 0,1 (waves 0,1 in parallel)
    if (wid < 2) {
        const float v = Ag[(tbase + wid*64 + lane)*16 + hh];
        scan_to(v, wid);
    }
    // stage chunk-0 C/B/Bt into parity-0 buffers
    if (half == 0) {
        #pragma unroll
        for (int j = 0; j < 4; ++j)
            *reinterpret_cast<bf16x4*>(&sm.Bm[0][lt0 + j][cq0]) =
                (bf16x4){(__bf16)rb[j][0], (__bf16)rb[j][1], (__bf16)rb[j][2], (__bf16)rb[j][3]};
        #pragma unroll
        for (int q = 0; q < 4; ++q)
            *reinterpret_cast<bf16x4*>(
                reinterpret_cast<char*>(&sm.Bt[0][cq0 + q][0]) + swz(cq0 + q, lt0*2)) =
                (bf16x4){(__bf16)rb[0][q], (__bf16)rb[1][q], (__bf16)rb[2][q], (__bf16)rb[3][q]};
    } else {
        #pragma unroll
        for (int j = 0; j < 4; ++j)
            *reinterpret_cast<bf16x4*>(&sm.Cm[0][rr0 + 16*j][cq0]) =
                (bf16x4){(__bf16)rb[j][0], (__bf16)rb[j][1], (__bf16)rb[j][2], (__bf16)rb[j][3]};
    }
    bar_lds();   // tables[0],[1] + St + chunk-0 stage visible
    {   // stage Xt[0] (needs ds[0])
        const float dsl = sm.ds[0][xl];
        #pragma unroll
        for (int q = 0; q < 4; ++q)
            *reinterpret_cast<__bf16*>(
                reinterpret_cast<char*>(&sm.Xt[0][xp4 + q][0]) + swz(xp4 + q, xl*2)) =
                (__bf16)(rx[q] * dsl);
    }
    // chunk-1 loads (rb consumed above); wave0 preloads A(2)
    #pragma unroll
    for (int j = 0; j < 4; ++j) {
        const int row = (half == 0) ? (lt0 + j) : (rr0 + 16*j);
        const size_t go = ((tbase + 64 + row)*16 + hh)*(size_t)64 + cq0;
        *reinterpret_cast<float4*>(rb[j]) = (half == 0)
            ? *reinterpret_cast<const float4*>(&Bg[go])
            : *reinterpret_cast<const float4*>(&Cg[go]);
    }
    *reinterpret_cast<float4*>(rx) =
        *reinterpret_cast<const float4*>(&Xg[((tbase + 64 + xl)*16 + hh)*(size_t)64 + ph*32 + xp4]);
    if (wid == 0) aA = Ag[(tbase + 2*64 + lane)*16 + hh];
    bar_lds();   // Xt[0] visible

    f32x4 aoprev = {};
    int x0 = 0, x1 = 1, x2 = 2;   // Xt buffers: c%3, (c+1)%3, (c-1)%3

    // ---------------- chunk loop: ONE barrier per chunk ----------------
    for (int c = 0; c < 64; ++c) {
        const int ci = c & 1, nb = ci ^ 1;
        const int t0 = c & 3, t1 = (c+1) & 3, t2 = (c+2) & 3, t3 = (c+3) & 3;

        // ---- MFMA cluster: chunk c (g/ao/st) ----
        f32x4 g0 = {}, g1 = {}, aoacc = {}, stacc = {};
        #pragma unroll
        for (int ks = 0; ks < 2; ++ks) {
            const int k0 = ks*32 + fg*8;
            const bf16x8 aC  = *reinterpret_cast<const bf16x8*>(&sm.Cm[ci][iw2 + fr][k0]);
            const bf16x8 bB0 = *reinterpret_cast<const bf16x8*>(&sm.Bm[ci][jh      + fr][k0]);
            const bf16x8 bB1 = *reinterpret_cast<const bf16x8*>(&sm.Bm[ci][jh + 16 + fr][k0]);
            const bf16x8 bSt = *reinterpret_cast<const bf16x8*>(&sm.St16[ci][pt + fr][k0]);
            const bf16x8 aBt = *reinterpret_cast<const bf16x8*>(
                reinterpret_cast<const char*>(&sm.Bt[ci][iw2 + fr][0]) + swz(iw2 + fr, k0*2));
            const bf16x8 bXt = *reinterpret_cast<const bf16x8*>(
                reinterpret_cast<const char*>(&sm.Xt[x0][pt + fr][0]) + swz(pt + fr, k0*2));
            g0    = mfma16(aC,  bB0, g0);
            g1    = mfma16(aC,  bB1, g1);
            aoacc = mfma16(aC,  bSt, aoacc);
            stacc = mfma16(aBt, bXt, stacc);
        }
        // ---- ad(c-1) = M'(c-1) @ Xs(c-1) ----
        f32x4 ad = {};
        if (c > 0) {
            #pragma unroll
            for (int ks = 0; ks < 2; ++ks) {
                const int k0 = ks*32 + fg*8;
                const bf16x8 aM = *reinterpret_cast<const bf16x8*>(&sm.Mm[nb][iw2 + fr][k0]);
                const bf16x8 bX = *reinterpret_cast<const bf16x8*>(
                    reinterpret_cast<const char*>(&sm.Xt[x2][pt + fr][0]) + swz(pt + fr, k0*2));
                ad = mfma16(aM, bX, ad);
            }
        }
        // ---- scan(c+2) -> tables[t2] ----
        if (c <= 61 && wid == 0) scan_to(aA, t2);
        // ---- Y store(c-2) from sY[nb] ----
        if (c >= 2) {
            const float4 v = *reinterpret_cast<const float4*>(&sm.sY[nb][xl][xp4]);
            *reinterpret_cast<float4*>(
                &Yg[((tbase + (size_t)(c-2)*64 + xl)*16 + hh)*(size_t)64 + ph*32 + xp4]) = v;
        }
        // ---- stage(c+1) into parity-nb / Xt[x1] ----
        if (c < 63) {
            if (half == 0) {
                #pragma unroll
                for (int j = 0; j < 4; ++j)
                    *reinterpret_cast<bf16x4*>(&sm.Bm[nb][lt0 + j][cq0]) =
                        (bf16x4){(__bf16)rb[j][0], (__bf16)rb[j][1], (__bf16)rb[j][2], (__bf16)rb[j][3]};
                #pragma unroll
                for (int q = 0; q < 4; ++q)
                    *reinterpret_cast<bf16x4*>(
                        reinterpret_cast<char*>(&sm.Bt[nb][cq0 + q][0]) + swz(cq0 + q, lt0*2)) =
                        (bf16x4){(__bf16)rb[0][q], (__bf16)rb[1][q], (__bf16)rb[2][q], (__bf16)rb[3][q]};
            } else {
                #pragma unroll
                for (int j = 0; j < 4; ++j)
                    *reinterpret_cast<bf16x4*>(&sm.Cm[nb][rr0 + 16*j][cq0]) =
                        (bf16x4){(__bf16)rb[j][0], (__bf16)rb[j][1], (__bf16)rb[j][2], (__bf16)rb[j][3]};
            }
            const float dsl = sm.ds[t1][xl];
            #pragma unroll
            for (int q = 0; q < 4; ++q)
                *reinterpret_cast<__bf16*>(
                    reinterpret_cast<char*>(&sm.Xt[x1][xp4 + q][0]) + swz(xp4 + q, xl*2)) =
                    (__bf16)(rx[q] * dsl);
        }
        // ---- prefetch chunk c+2 (rb consumed by stage above) ----
        if (c < 62) {
            const size_t s2 = tbase + (size_t)(c + 2)*64;
            #pragma unroll
            for (int j = 0; j < 4; ++j) {
                const int row = (half == 0) ? (lt0 + j) : (rr0 + 16*j);
                const size_t go = ((s2 + row)*16 + hh)*(size_t)64 + cq0;
                *reinterpret_cast<float4*>(rb[j]) = (half == 0)
                    ? *reinterpret_cast<const float4*>(&Bg[go])
                    : *reinterpret_cast<const float4*>(&Cg[go]);
            }
            *reinterpret_cast<float4*>(rx) =
                *reinterpret_cast<const float4*>(&Xg[((s2 + xl)*16 + hh)*(size_t)64 + ph*32 + xp4]);
        }
        if (wid == 0 && c <= 60) aA = Ag[(tbase + (size_t)(c + 3)*64 + lane)*16 + hh];
        // ---- sY[ci] write = Y(c-1) ----
        if (c > 0) {
            #pragma unroll
            for (int r = 0; r < 4; ++r) {
                const int i = iw2 + fg*4 + r;
                sm.sY[ci][i][pt + fr] = ad[r] + sm.dout[t3][i] * aoprev[r];
            }
        }
        // ---- Mm[ci] write = mask(G)*e^{cs_i-cs63} ----
        #pragma unroll
        for (int jt = 0; jt < 2; ++jt) {
            const int j = jh + jt*16 + fr;
            const f32x4& gg = jt ? g1 : g0;
            #pragma unroll
            for (int r = 0; r < 4; ++r) {
                const int i = iw2 + fg*4 + r;
                const float val = (i >= j) ? gg[r] * sm.douti[t0][i] : 0.0f;
                sm.Mm[ci][i][j] = (__bf16)val;
            }
        }
        // ---- St update -> St32 + St16[nb] ----
        if (c < 63) {
            const float dl = sm.dlast[t0];
            const int p = pt + fr, n0 = iw2 + fg*4;
            const float4 ov = *reinterpret_cast<const float4*>(&sm.St32[p][n0]);
            float4 nv;
            nv.x = fmaf(dl, ov.x, stacc[0]); nv.y = fmaf(dl, ov.y, stacc[1]);
            nv.z = fmaf(dl, ov.z, stacc[2]); nv.w = fmaf(dl, ov.w, stacc[3]);
            *reinterpret_cast<float4*>(&sm.St32[p][n0]) = nv;
            *reinterpret_cast<bf16x4*>(&sm.St16[nb][p][n0]) =
                (bf16x4){(__bf16)nv.x, (__bf16)nv.y, (__bf16)nv.z, (__bf16)nv.w};
        }
        aoprev = aoacc;
        bar_lds();   // the ONE barrier
        const int xt = x0; x0 = x1; x1 = x2; x2 = xt;   // rotate Xt buffers
    }

    // ---------------- epilogue: ad(63), Y(62), Y(63) ----------------
    {
        f32x4 ad = {};
        #pragma unroll
        for (int ks = 0; ks < 2; ++ks) {
            const int k0 = ks*32 + fg*8;
            const bf16x8 aM = *reinterpret_cast<const bf16x8*>(&sm.Mm[1][iw2 + fr][k0]);
            const bf16x8 bX = *reinterpret_cast<const bf16x8*>(
                reinterpret_cast<const char*>(&sm.Xt[x2][pt + fr][0]) + swz(pt + fr, k0*2));
            ad = mfma16(aM, bX, ad);
        }
        #pragma unroll
        for (int r = 0; r < 4; ++r) {
            const int i = iw2 + fg*4 + r;
            sm.sY[0][i][pt + fr] = ad[r] + sm.dout[3][i] * aoprev[r];
        }
    }
    {   // Y(62) from sY[1] (written in phase 63; loop-end barrier synced)
        const float4 v = *reinterpret_cast<const float4*>(&sm.sY[1][xl][xp4]);
        *reinterpret_cast<float4*>(
            &Yg[((tbase + (size_t)62*64 + xl)*16 + hh)*(size_t)64 + ph*32 + xp4]) = v;
    }
    bar_lds();
    {   // Y(63) from sY[0]
        const float4 v = *reinterpret_cast<const float4*>(&sm.sY[0][xl][xp4]);
        *reinterpret_cast<float4*>(
            &Yg[((tbase + (size_t)63*64 + xl)*16 + hh)*(size_t)64 + ph*32 + xp4]) = v;
    }
}

extern "C" void kernel_launch(void* const* d_in, const int* in_sizes, int n_in,
                              void* d_out, int out_size, void* d_ws, size_t ws_size,
                              hipStream_t stream) {
    const float* X  = (const float*)d_in[0];
    const float* I  = (const float*)d_in[1];
    const float* A  = (const float*)d_in[2];
    const float* Bp = (const float*)d_in[3];
    const float* Cp = (const float*)d_in[4];
    float* Y = (float*)d_out;
    ssd_fused<<<dim3(2, 16, 8), 512, 0, stream>>>(X, I, A, Bp, Cp, Y);
}